// Round 1
// baseline (32427.078 us; speedup 1.0000x reference)
//
#include <hip/hip_runtime.h>

#define T_STEPS 1000
#define NIN     128
#define NREC    512
#define NBATCH  64
#define ALPHA   0.2f

// ---------------------------------------------------------------------------
// Kernel A: W_eff[k][j] = ei[k] * w_rec[k][j] * autapse[k][j]
// (ei_mask is a diagonal matrix; left-multiply scales ROWS by ei[k])
// ---------------------------------------------------------------------------
__global__ void weff_kernel(const float* __restrict__ w_rec,
                            const float* __restrict__ ei_mask,
                            const float* __restrict__ autapse,
                            float* __restrict__ w_eff) {
    int idx = blockIdx.x * blockDim.x + threadIdx.x;
    if (idx < NREC * NREC) {
        int row = idx >> 9;                      // / 512
        float ei = ei_mask[row * NREC + row];    // diagonal element
        w_eff[idx] = ei * w_rec[idx] * autapse[idx];
    }
}

// ---------------------------------------------------------------------------
// Kernel B: inp_all[m][j] = sum_k x[m][k] * w_in[k][j] + b_rec[j]
// M = 64000 (b*1000+t), K = 128, N = 512.  Written into d_out (in-place
// consumed by the recurrence kernel: element (b,t,j) is read before being
// overwritten by the same thread in the same timestep).
// Block: 1024 threads, 32-row tile, all 512 cols.
//   tid -> j0 = tid & 255 (also j0+256), rg = tid >> 8 (4 row groups of 8)
// ---------------------------------------------------------------------------
__global__ __launch_bounds__(1024) void gemm_in_kernel(
        const float* __restrict__ x,
        const float* __restrict__ w_in,
        const float* __restrict__ b_rec,
        float* __restrict__ io) {
    __shared__ float xs[32][NIN];    // 16 KB

    const int tid = threadIdx.x;
    const int m0  = blockIdx.x * 32;

    // stage x tile: 32*128 = 4096 floats, 1024 threads * 1 float4
    {
        const float4* src = reinterpret_cast<const float4*>(x + (size_t)m0 * NIN);
        float4 v = src[tid];
        reinterpret_cast<float4*>(&xs[0][0])[tid] = v;
    }
    __syncthreads();

    const int j0 = tid & 255;
    const int j1 = j0 + 256;
    const int rg = tid >> 8;         // 0..3, rows rg*8 .. rg*8+7

    float acc[8][2];
#pragma unroll
    for (int i = 0; i < 8; ++i) { acc[i][0] = 0.f; acc[i][1] = 0.f; }

#pragma unroll 4
    for (int k = 0; k < NIN; ++k) {
        float wv0 = w_in[k * NREC + j0];
        float wv1 = w_in[k * NREC + j1];
#pragma unroll
        for (int i = 0; i < 8; ++i) {
            float xv = xs[rg * 8 + i][k];      // wave-uniform -> LDS broadcast
            acc[i][0] = fmaf(xv, wv0, acc[i][0]);
            acc[i][1] = fmaf(xv, wv1, acc[i][1]);
        }
    }

    const float br0 = b_rec[j0];
    const float br1 = b_rec[j1];
#pragma unroll
    for (int i = 0; i < 8; ++i) {
        size_t ro = (size_t)(m0 + rg * 8 + i) * NREC;
        io[ro + j0] = acc[i][0] + br0;
        io[ro + j1] = acc[i][1] + br1;
    }
}

// ---------------------------------------------------------------------------
// Kernel C: the recurrence. One block per batch element, 1024 threads.
// Thread (j = tid&511, half = tid>>9) computes the half-K partial dot for
// neuron j; halves combine through LDS. h lives in LDS (fp32, exact).
// W_eff (1 MB fp32) streams from L2 every step -> per-CU L2 BW bound.
// ---------------------------------------------------------------------------
__global__ __launch_bounds__(1024) void rnn_kernel(
        const float* __restrict__ W,        // [512][512] row-major
        const float* __restrict__ noise,    // [64][1000][512]
        float* __restrict__ io) {           // in: inp_all, out: h trajectory
    __shared__ float h[NREC];
    __shared__ float part[NREC];

    const int tid  = threadIdx.x;
    const int j    = tid & (NREC - 1);
    const int half = tid >> 9;              // 0 or 1
    const int b    = blockIdx.x;

    if (tid < NREC) h[tid] = 0.f;
    float hj = 0.f;                          // only meaningful for half==0
    __syncthreads();

    const int kb = half * 256;
    const float* wp = W + (size_t)kb * NREC + j;
    const size_t base = (size_t)b * T_STEPS * NREC + j;

    for (int t = 0; t < T_STEPS; ++t) {
        const size_t off = base + (size_t)t * NREC;

        float acc = (half == 0) ? (io[off] + noise[off]) : 0.f;

        // 256-long partial dot, unroll 16 for memory-level parallelism
#pragma unroll
        for (int ku = 0; ku < 256; ku += 16) {
            float w[16];
#pragma unroll
            for (int u = 0; u < 16; ++u)
                w[u] = wp[(size_t)(ku + u) * NREC];
            float hh[16];
#pragma unroll
            for (int u = 0; u < 16; ++u)
                hh[u] = h[kb + ku + u];       // wave-uniform broadcast
#pragma unroll
            for (int u = 0; u < 16; ++u)
                acc = fmaf(hh[u], w[u], acc);
        }

        if (half == 1) part[j] = acc;
        __syncthreads();                      // partials ready; all h reads done

        if (half == 0) {
            float pre  = acc + part[j];
            float hnew = (1.f - ALPHA) * hj + ALPHA * fmaxf(pre, 0.f);
            io[off] = hnew;
            h[j] = hnew;
            hj = hnew;
        }
        __syncthreads();                      // h ready for next step
    }
}

// ---------------------------------------------------------------------------
extern "C" void kernel_launch(void* const* d_in, const int* in_sizes, int n_in,
                              void* d_out, int out_size, void* d_ws, size_t ws_size,
                              hipStream_t stream) {
    const float* x       = (const float*)d_in[0];
    const float* w_in    = (const float*)d_in[1];
    const float* w_rec   = (const float*)d_in[2];
    const float* b_rec   = (const float*)d_in[3];
    const float* ei_mask = (const float*)d_in[4];
    const float* autapse = (const float*)d_in[5];
    const float* noise   = (const float*)d_in[6];
    float* out = (float*)d_out;
    float* W   = (float*)d_ws;                 // 512*512 fp32 = 1 MB scratch

    weff_kernel<<<dim3((NREC * NREC + 255) / 256), dim3(256), 0, stream>>>(
        w_rec, ei_mask, autapse, W);

    gemm_in_kernel<<<dim3(64000 / 32), dim3(1024), 0, stream>>>(
        x, w_in, b_rec, out);

    rnn_kernel<<<dim3(NBATCH), dim3(1024), 0, stream>>>(W, noise, out);
}

// Round 2
// 9476.252 us; speedup vs baseline: 3.4219x; 3.4219x over previous
//
#include <hip/hip_runtime.h>

#define T_STEPS 1000
#define NIN     128
#define NREC    512
#define NBATCH  64
#define ALPHA   0.2f

#define NSLICE  4          // blocks per batch element
#define SCOLS   128        // columns per slice (512/4)
#define KG      4          // k groups per block (threads 512 = KG*SCOLS)
#define KPER    128        // k elements per group

// d_ws layout (bytes):
//   [0, 1MB)                 W_eff (512x512 fp32)
//   [1MB, 1MB+256KB)         comm: 2 parities x 64 batches x 512 floats
//   [1MB+256KB, +1KB)        flags: 64 x 4 ints (steps completed per slice)
#define WS_W_OFF     0
#define WS_COMM_OFF  (1u << 20)
#define COMM_PAR     (NBATCH * NREC)                       // floats per parity
#define WS_FLAG_OFF  (WS_COMM_OFF + 2 * COMM_PAR * 4)
#define WS_NEEDED    (WS_FLAG_OFF + NBATCH * NSLICE * 4)

// ---------------------------------------------------------------------------
// W_eff[k][j] = ei[k] * w_rec[k][j] * autapse[k][j]
// ---------------------------------------------------------------------------
__global__ void weff_kernel(const float* __restrict__ w_rec,
                            const float* __restrict__ ei_mask,
                            const float* __restrict__ autapse,
                            float* __restrict__ w_eff) {
    int idx = blockIdx.x * blockDim.x + threadIdx.x;
    if (idx < NREC * NREC) {
        int row = idx >> 9;
        float ei = ei_mask[row * NREC + row];
        w_eff[idx] = ei * w_rec[idx] * autapse[idx];
    }
}

// ---------------------------------------------------------------------------
// inp_all[m][j] = sum_k x[m][k] * w_in[k][j] + b_rec[j]   (into d_out)
// ---------------------------------------------------------------------------
__global__ __launch_bounds__(1024) void gemm_in_kernel(
        const float* __restrict__ x,
        const float* __restrict__ w_in,
        const float* __restrict__ b_rec,
        float* __restrict__ io) {
    __shared__ float xs[32][NIN];

    const int tid = threadIdx.x;
    const int m0  = blockIdx.x * 32;

    {
        const float4* src = reinterpret_cast<const float4*>(x + (size_t)m0 * NIN);
        reinterpret_cast<float4*>(&xs[0][0])[tid] = src[tid];
    }
    __syncthreads();

    const int j0 = tid & 255;
    const int j1 = j0 + 256;
    const int rg = tid >> 8;

    float acc[8][2];
#pragma unroll
    for (int i = 0; i < 8; ++i) { acc[i][0] = 0.f; acc[i][1] = 0.f; }

#pragma unroll 4
    for (int k = 0; k < NIN; ++k) {
        float wv0 = w_in[k * NREC + j0];
        float wv1 = w_in[k * NREC + j1];
#pragma unroll
        for (int i = 0; i < 8; ++i) {
            float xv = xs[rg * 8 + i][k];
            acc[i][0] = fmaf(xv, wv0, acc[i][0]);
            acc[i][1] = fmaf(xv, wv1, acc[i][1]);
        }
    }

    const float br0 = b_rec[j0];
    const float br1 = b_rec[j1];
#pragma unroll
    for (int i = 0; i < 8; ++i) {
        size_t ro = (size_t)(m0 + rg * 8 + i) * NREC;
        io[ro + j0] = acc[i][0] + br0;
        io[ro + j1] = acc[i][1] + br1;
    }
}

// ---------------------------------------------------------------------------
// Cooperative recurrence: 256 blocks (batch b = blk>>2, slice s = blk&3),
// 512 threads (jl = tid&127 local column, kg = tid>>7 k-group).
// W slice (512 x 128 cols) register-resident: 128 VGPRs/thread.
// Per-step h all-gather among the 4 blocks of a batch via device-scope
// comm buffer (parity double-buffered) + release/acquire step flags.
// ---------------------------------------------------------------------------
__global__ __launch_bounds__(512, 2) void rnn_coop(
        const float* __restrict__ W,
        const float* __restrict__ noise,
        float* __restrict__ io,
        float* __restrict__ comm,
        int* __restrict__ flags) {
    __shared__ __align__(16) float h_lds[NREC];
    __shared__ float part[KG * SCOLS];

    const int tid = threadIdx.x;
    const int b   = blockIdx.x >> 2;
    const int s   = blockIdx.x & 3;
    const int jl  = tid & (SCOLS - 1);
    const int kg  = tid >> 7;
    const int jg  = s * SCOLS + jl;

    // one-time load of the W slice into registers (coalesced across lanes)
    float Wr[KPER];
    {
        const float* wp = W + (size_t)(kg * KPER) * NREC + jg;
#pragma unroll
        for (int u = 0; u < KPER; ++u)
            Wr[u] = wp[(size_t)u * NREC];
    }

    h_lds[tid] = 0.f;            // tid covers all 512 entries
    __syncthreads();

    float hj = 0.f;                                   // leaders' own h (tid<128)
    const size_t iobase = (size_t)b * T_STEPS * NREC + jg;
    int* const myflag = &flags[b * NSLICE + s];

    for (int t = 0; t < T_STEPS; ++t) {
        // prefetch this step's input projection + noise (leaders only)
        float inp = 0.f, nz = 0.f;
        if (tid < SCOLS) {
            size_t off = iobase + (size_t)t * NREC;
            inp = io[off];
            nz  = noise[off];
        }

        if (t > 0) {
            // 3 lanes spin on the 3 remote slices' step flags
            if (tid >= SCOLS && tid < SCOLS + 3) {
                const int rs = (s + (tid - SCOLS) + 1) & 3;
                const int* fp = &flags[b * NSLICE + rs];
                while (__hip_atomic_load(fp, __ATOMIC_ACQUIRE,
                                         __HIP_MEMORY_SCOPE_AGENT) < t)
                    __builtin_amdgcn_s_sleep(1);
            }
            __syncthreads();
            // gather remote h_t (384 floats) from the coherent comm buffer
            if (tid < 3 * SCOLS) {
                const int i  = tid >> 7;               // 0..2
                const int rs = (s + i + 1) & 3;
                const int jr = tid & (SCOLS - 1);
                const float* cp = comm + (size_t)(t & 1) * COMM_PAR
                                  + b * NREC + rs * SCOLS + jr;
                h_lds[rs * SCOLS + jr] =
                    __hip_atomic_load(cp, __ATOMIC_RELAXED,
                                      __HIP_MEMORY_SCOPE_AGENT);
            }
            __syncthreads();
        }

        // 128-long partial dot: uniform-address LDS reads broadcast to the wave
        float a0 = 0.f, a1 = 0.f, a2 = 0.f, a3 = 0.f;
        const float4* h4 = reinterpret_cast<const float4*>(&h_lds[kg * KPER]);
#pragma unroll
        for (int u = 0; u < KPER / 4; ++u) {
            float4 hv = h4[u];
            a0 = fmaf(hv.x, Wr[4 * u + 0], a0);
            a1 = fmaf(hv.y, Wr[4 * u + 1], a1);
            a2 = fmaf(hv.z, Wr[4 * u + 2], a2);
            a3 = fmaf(hv.w, Wr[4 * u + 3], a3);
        }
        part[kg * SCOLS + jl] = (a0 + a1) + (a2 + a3);
        __syncthreads();

        if (tid < SCOLS) {
            float pre  = inp + nz + part[tid] + part[SCOLS + tid]
                       + part[2 * SCOLS + tid] + part[3 * SCOLS + tid];
            float hnew = (1.f - ALPHA) * hj + ALPHA * fmaxf(pre, 0.f);
            hj = hnew;
            size_t off = iobase + (size_t)t * NREC;
            io[off]    = hnew;                        // trajectory output
            h_lds[jg]  = hnew;                        // own slice for next step
            float* cw = comm + (size_t)((t + 1) & 1) * COMM_PAR + b * NREC + jg;
            __hip_atomic_store(cw, hnew, __ATOMIC_RELAXED,
                               __HIP_MEMORY_SCOPE_AGENT);
        }
        __syncthreads();   // waves drain vmcnt before barrier -> comm visible
        if (tid == 0)
            __hip_atomic_store(myflag, t + 1, __ATOMIC_RELEASE,
                               __HIP_MEMORY_SCOPE_AGENT);
    }
}

// ---------------------------------------------------------------------------
// Fallback (round-1 kernel) if ws_size is too small for comm buffers.
// ---------------------------------------------------------------------------
__global__ __launch_bounds__(1024) void rnn_kernel(
        const float* __restrict__ W,
        const float* __restrict__ noise,
        float* __restrict__ io) {
    __shared__ float h[NREC];
    __shared__ float part[NREC];

    const int tid  = threadIdx.x;
    const int j    = tid & (NREC - 1);
    const int half = tid >> 9;
    const int b    = blockIdx.x;

    if (tid < NREC) h[tid] = 0.f;
    float hj = 0.f;
    __syncthreads();

    const int kb = half * 256;
    const float* wp = W + (size_t)kb * NREC + j;
    const size_t base = (size_t)b * T_STEPS * NREC + j;

    for (int t = 0; t < T_STEPS; ++t) {
        const size_t off = base + (size_t)t * NREC;
        float acc = (half == 0) ? (io[off] + noise[off]) : 0.f;
#pragma unroll
        for (int ku = 0; ku < 256; ku += 16) {
            float w[16];
#pragma unroll
            for (int u = 0; u < 16; ++u) w[u] = wp[(size_t)(ku + u) * NREC];
#pragma unroll
            for (int u = 0; u < 16; ++u) acc = fmaf(h[kb + ku + u], w[u], acc);
        }
        if (half == 1) part[j] = acc;
        __syncthreads();
        if (half == 0) {
            float pre  = acc + part[j];
            float hnew = (1.f - ALPHA) * hj + ALPHA * fmaxf(pre, 0.f);
            io[off] = hnew;
            h[j] = hnew;
            hj = hnew;
        }
        __syncthreads();
    }
}

// ---------------------------------------------------------------------------
extern "C" void kernel_launch(void* const* d_in, const int* in_sizes, int n_in,
                              void* d_out, int out_size, void* d_ws, size_t ws_size,
                              hipStream_t stream) {
    const float* x       = (const float*)d_in[0];
    const float* w_in    = (const float*)d_in[1];
    const float* w_rec   = (const float*)d_in[2];
    const float* b_rec   = (const float*)d_in[3];
    const float* ei_mask = (const float*)d_in[4];
    const float* autapse = (const float*)d_in[5];
    const float* noise   = (const float*)d_in[6];
    float* out = (float*)d_out;

    char* ws = (char*)d_ws;
    float* W     = (float*)(ws + WS_W_OFF);
    float* comm  = (float*)(ws + WS_COMM_OFF);
    int*   flags = (int*)(ws + WS_FLAG_OFF);

    weff_kernel<<<dim3((NREC * NREC + 255) / 256), dim3(256), 0, stream>>>(
        w_rec, ei_mask, autapse, W);

    gemm_in_kernel<<<dim3(64000 / 32), dim3(1024), 0, stream>>>(
        x, w_in, b_rec, out);

    if (ws_size >= (size_t)WS_NEEDED) {
        hipMemsetAsync(flags, 0, NBATCH * NSLICE * sizeof(int), stream);
        void* args[] = {(void*)&W, (void*)&noise, (void*)&out,
                        (void*)&comm, (void*)&flags};
        hipLaunchCooperativeKernel(reinterpret_cast<void*>(rnn_coop),
                                   dim3(NBATCH * NSLICE), dim3(512),
                                   args, 0, stream);
    } else {
        rnn_kernel<<<dim3(NBATCH), dim3(1024), 0, stream>>>(W, noise, out);
    }
}

// Round 3
// 2607.234 us; speedup vs baseline: 12.4373x; 3.6346x over previous
//
#include <hip/hip_runtime.h>

#define T_STEPS 1000
#define NIN     128
#define NREC    512
#define NBATCH  64
#define ALPHA   0.2f

#define NSLICE  4          // blocks per batch element
#define SCOLS   128        // columns per slice (512/4)
#define KPER    128        // k elements per k-group (4 groups of 2 waves)

// d_ws layout (bytes):
//   [0, 1MB)            W_eff (512x512 fp32)
//   [1MB, +256KB)       comm: 2 parities x 64 batches x 512 floats
//   [1MB+256KB, +2KB)   flags: 64 batches x 4 slices x 2 leader-waves
#define WS_W_OFF     0
#define WS_COMM_OFF  (1u << 20)
#define COMM_PAR     (NBATCH * NREC)
#define WS_FLAG_OFF  (WS_COMM_OFF + 2 * COMM_PAR * 4)
#define N_FLAGS      (NBATCH * NSLICE * 2)
#define WS_NEEDED    (WS_FLAG_OFF + N_FLAGS * 4)

// ---------------------------------------------------------------------------
// W_eff[k][j] = ei[k] * w_rec[k][j] * autapse[k][j]
// ---------------------------------------------------------------------------
__global__ void weff_kernel(const float* __restrict__ w_rec,
                            const float* __restrict__ ei_mask,
                            const float* __restrict__ autapse,
                            float* __restrict__ w_eff) {
    int idx = blockIdx.x * blockDim.x + threadIdx.x;
    if (idx < NREC * NREC) {
        int row = idx >> 9;
        float ei = ei_mask[row * NREC + row];
        w_eff[idx] = ei * w_rec[idx] * autapse[idx];
    }
}

// ---------------------------------------------------------------------------
// inp_all[m][j] = sum_k x[m][k] * w_in[k][j] + b_rec[j]   (into d_out)
// ---------------------------------------------------------------------------
__global__ __launch_bounds__(1024) void gemm_in_kernel(
        const float* __restrict__ x,
        const float* __restrict__ w_in,
        const float* __restrict__ b_rec,
        float* __restrict__ io) {
    __shared__ float xs[32][NIN];

    const int tid = threadIdx.x;
    const int m0  = blockIdx.x * 32;

    {
        const float4* src = reinterpret_cast<const float4*>(x + (size_t)m0 * NIN);
        reinterpret_cast<float4*>(&xs[0][0])[tid] = src[tid];
    }
    __syncthreads();

    const int j0 = tid & 255;
    const int j1 = j0 + 256;
    const int rg = tid >> 8;

    float acc[8][2];
#pragma unroll
    for (int i = 0; i < 8; ++i) { acc[i][0] = 0.f; acc[i][1] = 0.f; }

#pragma unroll 4
    for (int k = 0; k < NIN; ++k) {
        float wv0 = w_in[k * NREC + j0];
        float wv1 = w_in[k * NREC + j1];
#pragma unroll
        for (int i = 0; i < 8; ++i) {
            float xv = xs[rg * 8 + i][k];
            acc[i][0] = fmaf(xv, wv0, acc[i][0]);
            acc[i][1] = fmaf(xv, wv1, acc[i][1]);
        }
    }

    const float br0 = b_rec[j0];
    const float br1 = b_rec[j1];
#pragma unroll
    for (int i = 0; i < 8; ++i) {
        size_t ro = (size_t)(m0 + rg * 8 + i) * NREC;
        io[ro + j0] = acc[i][0] + br0;
        io[ro + j1] = acc[i][1] + br1;
    }
}

// ---------------------------------------------------------------------------
// Cooperative recurrence. 256 blocks: batch b = blk>>2, slice s = blk&3.
// 512 threads: jl = tid&127 (column within slice), kg = tid>>7 (k-quarter).
// Thread (kg,jl) holds W[kg*128 .. +128)[s*128+jl] in 128 pinned VGPRs.
// Per step: k-group kg needs slice kg's h. kg==s: already in LDS (own h,
// written by leaders last step). kg!=s: 2-lane spin on slice kg's per-wave
// flags (relaxed, LLC-coherent), then per-wave redundant gather into LDS
// (no cross-wave dependency -> no barrier before compute).
// Only 2 workgroup barriers per step. No acquire/release fences at all:
// writer drains comm stores with explicit vmcnt(0) before setting flags.
// ---------------------------------------------------------------------------
__global__ __launch_bounds__(512, 2) void rnn_coop(
        const float* __restrict__ W,
        const float* __restrict__ noise,
        float* __restrict__ io,
        float* __restrict__ comm,
        int* __restrict__ flags) {
    __shared__ __align__(16) float h_lds[NREC];
    __shared__ float part[3 * SCOLS];

    const int tid = threadIdx.x;
    const int b   = blockIdx.x >> 2;
    const int s   = blockIdx.x & 3;
    const int jl  = tid & (SCOLS - 1);
    const int kg  = tid >> 7;          // 0..3
    const int ln  = tid & 63;
    const int jg  = s * SCOLS + jl;

    // one-time W slice load (coalesced), then PIN in VGPRs:
    float Wr[KPER];
    {
        const float* wp = W + (size_t)(kg * KPER) * NREC + jg;
#pragma unroll
        for (int u = 0; u < KPER; ++u)
            Wr[u] = wp[(size_t)u * NREC];
    }
#pragma unroll
    for (int u = 0; u < KPER; ++u)
        asm volatile("" : "+v"(Wr[u]));   // forbid remat/reload from memory

    h_lds[tid] = 0.f;                      // covers all 512
    __syncthreads();

    float hj = 0.f;                        // leaders' (tid<128) own h
    const size_t iobase = (size_t)b * T_STEPS * NREC + jg;
    const int fbase = b * NSLICE * 2;

    for (int t = 0; t < T_STEPS; ++t) {
        // issue this step's input-projection + noise loads early (leaders)
        const size_t off = iobase + (size_t)t * NREC;
        float inp = 0.f, nz = 0.f;
        if (tid < SCOLS) { inp = io[off]; nz = noise[off]; }

        if (t > 0 && kg != s) {
            if (ln < 2) {
                const int* fp = &flags[fbase + kg * 2 + ln];
                while (__hip_atomic_load(fp, __ATOMIC_RELAXED,
                                         __HIP_MEMORY_SCOPE_AGENT) < t)
                    __builtin_amdgcn_s_sleep(1);
            }
            // wave has one PC: all lanes are past the spin here. Block the
            // compiler from hoisting the gather loads above it:
            asm volatile("" ::: "memory");
            const float* cp = comm + (size_t)(t & 1) * COMM_PAR
                              + b * NREC + kg * SCOLS;
            float v0 = __hip_atomic_load(cp + ln, __ATOMIC_RELAXED,
                                         __HIP_MEMORY_SCOPE_AGENT);
            float v1 = __hip_atomic_load(cp + 64 + ln, __ATOMIC_RELAXED,
                                         __HIP_MEMORY_SCOPE_AGENT);
            // each wave writes ALL 128 values it will read: no cross-wave dep
            h_lds[kg * SCOLS + ln]      = v0;
            h_lds[kg * SCOLS + 64 + ln] = v1;
        }

        // 128-long partial dot against pinned W regs (uniform LDS broadcast)
        float a0 = 0.f, a1 = 0.f, a2 = 0.f, a3 = 0.f;
        const float4* h4 = reinterpret_cast<const float4*>(&h_lds[kg * KPER]);
#pragma unroll
        for (int u = 0; u < KPER / 4; ++u) {
            float4 hv = h4[u];
            a0 = fmaf(hv.x, Wr[4 * u + 0], a0);
            a1 = fmaf(hv.y, Wr[4 * u + 1], a1);
            a2 = fmaf(hv.z, Wr[4 * u + 2], a2);
            a3 = fmaf(hv.w, Wr[4 * u + 3], a3);
        }
        float psum = (a0 + a1) + (a2 + a3);
        if (kg != 0) part[(kg - 1) * SCOLS + jl] = psum;
        __syncthreads();                               // B1: partials ready

        if (tid < SCOLS) {
            float pre  = inp + nz + psum + part[jl]
                       + part[SCOLS + jl] + part[2 * SCOLS + jl];
            float hnew = (1.f - ALPHA) * hj + ALPHA * fmaxf(pre, 0.f);
            hj = hnew;
            h_lds[jg] = hnew;                          // own slice for t+1
            float* cw = comm + (size_t)((t + 1) & 1) * COMM_PAR + b * NREC + jg;
            __hip_atomic_store(cw, hnew, __ATOMIC_RELAXED,
                               __HIP_MEMORY_SCOPE_AGENT);
            asm volatile("s_waitcnt vmcnt(0)" ::: "memory");  // comm at LLC
            if (ln == 0) {
                int* mf = &flags[fbase + s * 2 + (tid >> 6)];
                __hip_atomic_store(mf, t + 1, __ATOMIC_RELAXED,
                                   __HIP_MEMORY_SCOPE_AGENT);
            }
            io[off] = hnew;                            // after flag; no rush
        }
        __syncthreads();                               // B2: h_lds ready
    }
}

// ---------------------------------------------------------------------------
// Fallback (round-1 kernel) if ws_size is too small for comm buffers.
// ---------------------------------------------------------------------------
__global__ __launch_bounds__(1024) void rnn_kernel(
        const float* __restrict__ W,
        const float* __restrict__ noise,
        float* __restrict__ io) {
    __shared__ float h[NREC];
    __shared__ float part[NREC];

    const int tid  = threadIdx.x;
    const int j    = tid & (NREC - 1);
    const int half = tid >> 9;
    const int b    = blockIdx.x;

    if (tid < NREC) h[tid] = 0.f;
    float hj = 0.f;
    __syncthreads();

    const int kb = half * 256;
    const float* wp = W + (size_t)kb * NREC + j;
    const size_t base = (size_t)b * T_STEPS * NREC + j;

    for (int t = 0; t < T_STEPS; ++t) {
        const size_t off = base + (size_t)t * NREC;
        float acc = (half == 0) ? (io[off] + noise[off]) : 0.f;
#pragma unroll
        for (int ku = 0; ku < 256; ku += 16) {
            float w[16];
#pragma unroll
            for (int u = 0; u < 16; ++u) w[u] = wp[(size_t)(ku + u) * NREC];
#pragma unroll
            for (int u = 0; u < 16; ++u) acc = fmaf(h[kb + ku + u], w[u], acc);
        }
        if (half == 1) part[j] = acc;
        __syncthreads();
        if (half == 0) {
            float pre  = acc + part[j];
            float hnew = (1.f - ALPHA) * hj + ALPHA * fmaxf(pre, 0.f);
            io[off] = hnew;
            h[j] = hnew;
            hj = hnew;
        }
        __syncthreads();
    }
}

// ---------------------------------------------------------------------------
extern "C" void kernel_launch(void* const* d_in, const int* in_sizes, int n_in,
                              void* d_out, int out_size, void* d_ws, size_t ws_size,
                              hipStream_t stream) {
    const float* x       = (const float*)d_in[0];
    const float* w_in    = (const float*)d_in[1];
    const float* w_rec   = (const float*)d_in[2];
    const float* b_rec   = (const float*)d_in[3];
    const float* ei_mask = (const float*)d_in[4];
    const float* autapse = (const float*)d_in[5];
    const float* noise   = (const float*)d_in[6];
    float* out = (float*)d_out;

    char* ws = (char*)d_ws;
    float* W     = (float*)(ws + WS_W_OFF);
    float* comm  = (float*)(ws + WS_COMM_OFF);
    int*   flags = (int*)(ws + WS_FLAG_OFF);

    weff_kernel<<<dim3((NREC * NREC + 255) / 256), dim3(256), 0, stream>>>(
        w_rec, ei_mask, autapse, W);

    gemm_in_kernel<<<dim3(64000 / 32), dim3(1024), 0, stream>>>(
        x, w_in, b_rec, out);

    if (ws_size >= (size_t)WS_NEEDED) {
        hipMemsetAsync(flags, 0, N_FLAGS * sizeof(int), stream);
        void* args[] = {(void*)&W, (void*)&noise, (void*)&out,
                        (void*)&comm, (void*)&flags};
        hipLaunchCooperativeKernel(reinterpret_cast<void*>(rnn_coop),
                                   dim3(NBATCH * NSLICE), dim3(512),
                                   args, 0, stream);
    } else {
        rnn_kernel<<<dim3(NBATCH), dim3(1024), 0, stream>>>(W, noise, out);
    }
}

// Round 4
// 1683.613 us; speedup vs baseline: 19.2604x; 1.5486x over previous
//
#include <hip/hip_runtime.h>

#define T_STEPS 1000
#define NIN     128
#define NREC    512
#define NBATCH  64
#define ALPHA   0.2f

#define NSLICE  4          // blocks per batch element
#define SCOLS   128        // columns per slice (512/4)
#define NGRP    8          // k-groups per block (1024 threads / 128)
#define KPER    64         // k elements per group

// d_ws layout (bytes):
//   [0, 1MB)        W_eff (512x512 fp32)
//   [1MB, +512KB)   comm: 2 parities x 64 batches x 512 u64 {tag,h}
#define WS_W_OFF     0
#define WS_COMM_OFF  (1u << 20)
#define COMM_U64     (NBATCH * NREC)               // u64 elements per parity
#define WS_NEEDED    (WS_COMM_OFF + 2 * COMM_U64 * 8)

// ---------------------------------------------------------------------------
// W_eff[k][j] = ei[k] * w_rec[k][j] * autapse[k][j]
// ---------------------------------------------------------------------------
__global__ void weff_kernel(const float* __restrict__ w_rec,
                            const float* __restrict__ ei_mask,
                            const float* __restrict__ autapse,
                            float* __restrict__ w_eff) {
    int idx = blockIdx.x * blockDim.x + threadIdx.x;
    if (idx < NREC * NREC) {
        int row = idx >> 9;
        float ei = ei_mask[row * NREC + row];
        w_eff[idx] = ei * w_rec[idx] * autapse[idx];
    }
}

// ---------------------------------------------------------------------------
// inp_all[m][j] = sum_k x[m][k] * w_in[k][j] + b_rec[j]   (into d_out)
// ---------------------------------------------------------------------------
__global__ __launch_bounds__(1024) void gemm_in_kernel(
        const float* __restrict__ x,
        const float* __restrict__ w_in,
        const float* __restrict__ b_rec,
        float* __restrict__ io) {
    __shared__ float xs[32][NIN];

    const int tid = threadIdx.x;
    const int m0  = blockIdx.x * 32;

    {
        const float4* src = reinterpret_cast<const float4*>(x + (size_t)m0 * NIN);
        reinterpret_cast<float4*>(&xs[0][0])[tid] = src[tid];
    }
    __syncthreads();

    const int j0 = tid & 255;
    const int j1 = j0 + 256;
    const int rg = tid >> 8;

    float acc[8][2];
#pragma unroll
    for (int i = 0; i < 8; ++i) { acc[i][0] = 0.f; acc[i][1] = 0.f; }

#pragma unroll 4
    for (int k = 0; k < NIN; ++k) {
        float wv0 = w_in[k * NREC + j0];
        float wv1 = w_in[k * NREC + j1];
#pragma unroll
        for (int i = 0; i < 8; ++i) {
            float xv = xs[rg * 8 + i][k];
            acc[i][0] = fmaf(xv, wv0, acc[i][0]);
            acc[i][1] = fmaf(xv, wv1, acc[i][1]);
        }
    }

    const float br0 = b_rec[j0];
    const float br1 = b_rec[j1];
#pragma unroll
    for (int i = 0; i < 8; ++i) {
        size_t ro = (size_t)(m0 + rg * 8 + i) * NREC;
        io[ro + j0] = acc[i][0] + br0;
        io[ro + j1] = acc[i][1] + br1;
    }
}

// ---------------------------------------------------------------------------
// Cooperative recurrence. 256 blocks: batch b = blk>>2, slice s = blk&3.
// 1024 threads: jl = tid&127 (column), g = tid>>7 (k-group of 64).
// Thread (g,jl) holds W[g*64 .. +64)[s*128+jl] in 64 VGPRs (cap 128 at
// 16 waves/CU forbids AGPR spill of the slice -> real registers).
// Comm: u64 payload {tag = step, float bits}; single relaxed agent store,
// readers poll the payload itself (no flags, no vmcnt drain).
// ---------------------------------------------------------------------------
__global__ __launch_bounds__(1024, 4) void rnn_coop(
        const float* __restrict__ W,
        const float* __restrict__ noise,
        float* __restrict__ io,
        unsigned long long* __restrict__ comm) {
    __shared__ __align__(16) float h_lds[NREC];
    __shared__ float part[NGRP * SCOLS];

    const int tid = threadIdx.x;
    const int b   = blockIdx.x >> 2;
    const int s   = blockIdx.x & 3;
    const int jl  = tid & (SCOLS - 1);
    const int g   = tid >> 7;              // 0..7
    const int ln  = tid & 63;
    const int jg  = s * SCOLS + jl;
    const bool remote = (g >> 1) != s;     // this k-group's h slice is remote
    const int cslot = g * KPER + ln;       // h index this lane gathers

    // one-time W slice load (coalesced), then pin in VGPRs
    float Wr[KPER];
    {
        const float* wp = W + (size_t)(g * KPER) * NREC + jg;
#pragma unroll
        for (int u = 0; u < KPER; ++u)
            Wr[u] = wp[(size_t)u * NREC];
    }
#pragma unroll
    for (int u = 0; u < KPER; ++u)
        asm volatile("" : "+v"(Wr[u]));

    if (tid < NREC) h_lds[tid] = 0.f;
    __syncthreads();

    float hj = 0.f;                        // leaders' (tid<128) own h
    const size_t iobase = (size_t)b * T_STEPS * NREC + jg;
    const unsigned long long* cbase = comm + (size_t)b * NREC + cslot;
    unsigned long long* cwbase = comm + (size_t)b * NREC + jg;

    for (int t = 0; t < T_STEPS; ++t) {
        const size_t off = iobase + (size_t)t * NREC;
        float inp = 0.f, nz = 0.f;
        if (tid < SCOLS) { inp = io[off]; nz = noise[off]; }   // issue early

        if (t > 0 && remote) {
            const unsigned long long* cp = cbase + (size_t)(t & 1) * COMM_U64;
            unsigned long long v = __hip_atomic_load(
                cp, __ATOMIC_RELAXED, __HIP_MEMORY_SCOPE_AGENT);
            while ((int)(unsigned)(v >> 32) < t)
                v = __hip_atomic_load(cp, __ATOMIC_RELAXED,
                                      __HIP_MEMORY_SCOPE_AGENT);
            asm volatile("" ::: "memory");
            // each wave of the group writes the full 64-entry range it reads
            h_lds[cslot] = __uint_as_float((unsigned)(v & 0xffffffffu));
        }

        // 64-long partial dot against pinned W regs (uniform LDS broadcast)
        float a0 = 0.f, a1 = 0.f, a2 = 0.f, a3 = 0.f;
        const float4* h4 = reinterpret_cast<const float4*>(&h_lds[g * KPER]);
#pragma unroll
        for (int u = 0; u < KPER / 4; ++u) {
            float4 hv = h4[u];
            a0 = fmaf(hv.x, Wr[4 * u + 0], a0);
            a1 = fmaf(hv.y, Wr[4 * u + 1], a1);
            a2 = fmaf(hv.z, Wr[4 * u + 2], a2);
            a3 = fmaf(hv.w, Wr[4 * u + 3], a3);
        }
        part[g * SCOLS + jl] = (a0 + a1) + (a2 + a3);
        __syncthreads();                               // B1: partials ready

        if (tid < SCOLS) {
            float pre = inp + nz;
#pragma unroll
            for (int q = 0; q < NGRP; ++q)
                pre += part[q * SCOLS + jl];
            float hnew = (1.f - ALPHA) * hj + ALPHA * fmaxf(pre, 0.f);
            hj = hnew;
            h_lds[jg] = hnew;                          // own slice for t+1
            unsigned long long pv =
                ((unsigned long long)(unsigned)(t + 1) << 32) |
                (unsigned long long)__float_as_uint(hnew);
            __hip_atomic_store(cwbase + (size_t)((t + 1) & 1) * COMM_U64, pv,
                               __ATOMIC_RELAXED, __HIP_MEMORY_SCOPE_AGENT);
            io[off] = hnew;                            // trajectory output
        }
        __syncthreads();                               // B2: h_lds ready
    }
}

// ---------------------------------------------------------------------------
// Fallback (round-1 kernel) if ws_size is too small for comm buffers.
// ---------------------------------------------------------------------------
__global__ __launch_bounds__(1024) void rnn_kernel(
        const float* __restrict__ W,
        const float* __restrict__ noise,
        float* __restrict__ io) {
    __shared__ float h[NREC];
    __shared__ float part2[NREC];

    const int tid  = threadIdx.x;
    const int j    = tid & (NREC - 1);
    const int half = tid >> 9;
    const int b    = blockIdx.x;

    if (tid < NREC) h[tid] = 0.f;
    float hj = 0.f;
    __syncthreads();

    const int kb = half * 256;
    const float* wp = W + (size_t)kb * NREC + j;
    const size_t base = (size_t)b * T_STEPS * NREC + j;

    for (int t = 0; t < T_STEPS; ++t) {
        const size_t off = base + (size_t)t * NREC;
        float acc = (half == 0) ? (io[off] + noise[off]) : 0.f;
#pragma unroll
        for (int ku = 0; ku < 256; ku += 16) {
            float w[16];
#pragma unroll
            for (int u = 0; u < 16; ++u) w[u] = wp[(size_t)(ku + u) * NREC];
#pragma unroll
            for (int u = 0; u < 16; ++u) acc = fmaf(h[kb + ku + u], w[u], acc);
        }
        if (half == 1) part2[j] = acc;
        __syncthreads();
        if (half == 0) {
            float pre  = acc + part2[j];
            float hnew = (1.f - ALPHA) * hj + ALPHA * fmaxf(pre, 0.f);
            io[off] = hnew;
            h[j] = hnew;
            hj = hnew;
        }
        __syncthreads();
    }
}

// ---------------------------------------------------------------------------
extern "C" void kernel_launch(void* const* d_in, const int* in_sizes, int n_in,
                              void* d_out, int out_size, void* d_ws, size_t ws_size,
                              hipStream_t stream) {
    const float* x       = (const float*)d_in[0];
    const float* w_in    = (const float*)d_in[1];
    const float* w_rec   = (const float*)d_in[2];
    const float* b_rec   = (const float*)d_in[3];
    const float* ei_mask = (const float*)d_in[4];
    const float* autapse = (const float*)d_in[5];
    const float* noise   = (const float*)d_in[6];
    float* out = (float*)d_out;

    char* ws = (char*)d_ws;
    float* W = (float*)(ws + WS_W_OFF);
    unsigned long long* comm = (unsigned long long*)(ws + WS_COMM_OFF);

    weff_kernel<<<dim3((NREC * NREC + 255) / 256), dim3(256), 0, stream>>>(
        w_rec, ei_mask, autapse, W);

    gemm_in_kernel<<<dim3(64000 / 32), dim3(1024), 0, stream>>>(
        x, w_in, b_rec, out);

    if (ws_size >= (size_t)WS_NEEDED) {
        hipMemsetAsync(comm, 0, 2 * COMM_U64 * 8, stream);   // reset tags
        void* args[] = {(void*)&W, (void*)&noise, (void*)&out, (void*)&comm};
        hipLaunchCooperativeKernel(reinterpret_cast<void*>(rnn_coop),
                                   dim3(NBATCH * NSLICE), dim3(1024),
                                   args, 0, stream);
    } else {
        rnn_kernel<<<dim3(NBATCH), dim3(1024), 0, stream>>>(W, noise, out);
    }
}